// Round 7
// baseline (157.363 us; speedup 1.0000x reference)
//
#include <hip/hip_runtime.h>

#define NPF 16
#define NH 8
#define NV 16
#define NN 900
#define ND 256
#define NB 4
#define NM (NN * NN)          // 810000
#define TOTAL (NB * NM)       // 3240000
#define TOTAL4 (TOTAL / 4)    // 810000 float4 groups

typedef __fp16 half2v __attribute__((ext_vector_type(2)));
typedef float f4v __attribute__((ext_vector_type(4)));
union h2u { half2v h; unsigned int u; float f; };

#if __has_builtin(__builtin_amdgcn_fdot2)
__device__ __forceinline__ float fdot2f(half2v a, half2v b, float c) {
    return __builtin_amdgcn_fdot2(a, b, c, false);
}
#else
__device__ __forceinline__ float fdot2f(half2v a, half2v b, float c) {
    return fmaf((float)a.x, (float)b.x, fmaf((float)a.y, (float)b.y, c));
}
#endif

// ============================ Kernel A: imap (UNCHANGED) ============================
__global__ __launch_bounds__(256) void hough_imap(
    const float* __restrict__ queries,
    const float* __restrict__ cur_ref,
    const float* __restrict__ vote_w,
    const float* __restrict__ vote_b,
    float* __restrict__ xbuf)
{
    __shared__ __align__(16) float qs[ND];
    __shared__ float part[256];
    __shared__ float vp[NV * 2];
    __shared__ float s2i[NV];
    __shared__ __align__(16) float4 sCoef[NV];
    __shared__ float red[4];
    __shared__ float s_inv;

    const int tid = threadIdx.x;
    const int bn  = blockIdx.x;
    const int b   = bn / NN;
    const int n   = bn - b * NN;

    qs[tid] = queries[(size_t)bn * ND + tid];
    __syncthreads();

    {
        const int o     = tid & 31;
        const int chunk = tid >> 5;
        const float4* wv = (const float4*)(vote_w + o * ND + chunk * 32);
        const float4* qv = (const float4*)(qs + chunk * 32);
        float p = 0.f;
#pragma unroll
        for (int j = 0; j < 8; j++) {
            float4 w4 = wv[j];
            float4 q4 = qv[j];
            p += w4.x * q4.x + w4.y * q4.y + w4.z * q4.z + w4.w * q4.w;
        }
        part[tid] = p;
    }
    __syncthreads();

    if (tid < 32) {
        float s = vote_b[tid];
#pragma unroll
        for (int c = 0; c < 8; c++) s += part[c * 32 + tid];
        vp[tid] = s + cur_ref[((size_t)b * NN + n) * 4 + (tid & 1)];
    } else if (tid >= 64 && tid < 64 + NV) {
        // sigma quirk: sigma_flat[b, i] = sigma[b, i % N], i = n*V + v
        int v = tid - 64;
        int j = (n * NV + v) % NN;
        float c2 = cur_ref[((size_t)b * NN + j) * 4 + 2];
        float c3 = cur_ref[((size_t)b * NN + j) * 4 + 3];
        float sg = (c2 + c3) * 0.25f;   // mean(c2,c3)/2
        s2i[v] = 0.5f / (sg * sg);
    }
    __syncthreads();

    if (tid < NV) {
        float x  = vp[2 * tid];
        float y  = vp[2 * tid + 1];
        float s2 = s2i[tid];
        sCoef[tid] = make_float4(2.f * s2 * x, 2.f * s2 * y,
                                 -s2 * (x * x + y * y), -s2);
    }
    __syncthreads();

    float acc[4] = {0.f, 0.f, 0.f, 0.f};
    const float4* cr4 = (const float4*)cur_ref + (size_t)b * NN;

#pragma unroll 1
    for (int c = 0; c < 2; c++) {
        float ax[8], ay[8], c0[8], ns[8];
#pragma unroll
        for (int v = 0; v < 8; v++) {
            float4 f = sCoef[c * 8 + v];
            ax[v] = f.x; ay[v] = f.y; c0[v] = f.z; ns[v] = f.w;
        }
#pragma unroll
        for (int i = 0; i < 4; i++) {
            int m = tid + 256 * i;
            if (m < NN) {
                float4 cr = cr4[m];
                float cx = cr.x, cy = cr.y;
                float cc = cx * cx + cy * cy;
                float a = 0.f;
#pragma unroll
                for (int v = 0; v < 8; v++) {
                    float t = fmaf(ax[v], cx, c0[v]);
                    t = fmaf(ay[v], cy, t);
                    t = fmaf(ns[v], cc, t);
                    a += __expf(fminf(t, 0.f));
                }
                acc[i] += a;
            }
        }
    }

    float lsum = acc[0] + acc[1] + acc[2] + acc[3];
#pragma unroll
    for (int off = 32; off > 0; off >>= 1) lsum += __shfl_down(lsum, off, 64);
    if ((tid & 63) == 0) red[tid >> 6] = lsum;
    __syncthreads();
    if (tid == 0)
        s_inv = 1.0f / fmaxf(red[0] + red[1] + red[2] + red[3], 1e-12f);
    __syncthreads();
    const float inv = s_inv;

    float* xr = xbuf + (size_t)bn * NN;
#pragma unroll
    for (int i = 0; i < 4; i++) {
        int m = tid + 256 * i;
        if (m < NN) xr[m] = 1.0f - acc[i] * inv;
    }
}

// ==================== Kernel C: pack proj weights to half2 ====================
// wpk[0..63]  = half2(W[2j], W[2j+1]);  wpk[64..71] = bias bits (f32)
__global__ __launch_bounds__(128) void hough_pack(
    const float* __restrict__ proj_w,
    const float* __restrict__ proj_b,
    unsigned int* __restrict__ wpk)
{
    int t = threadIdx.x;
    if (t < 64) {
        h2u u;
        u.h = __builtin_amdgcn_cvt_pkrtz(proj_w[2 * t], proj_w[2 * t + 1]);
        wpk[t] = u.u;
    } else if (t < 72) {
        h2u u;
        u.f = proj_b[t - 64];
        wpk[t] = u.u;
    }
}

// ========================= Kernel B: epilogue =========================
// 4 consecutive elements / thread; trig once, packed half2; dot2 projection
// with SGPR weights; float4 nontemporal stores. Zero LDS.
__global__ __launch_bounds__(256)
__attribute__((amdgpu_waves_per_eu(6, 8)))
void hough_epi(
    const float* __restrict__ xbuf,
    const unsigned int* __restrict__ wpk,
    float* __restrict__ out)
{
    const int t4 = blockIdx.x * 256 + threadIdx.x;
    if (t4 >= TOTAL4) return;

    const float4 xv = ((const float4*)xbuf)[t4];
    const float xa[4] = {xv.x, xv.y, xv.z, xv.w};

    // 100 / 10000^(k/8)
    const float invt[8] = {100.0f, 31.622776601683793f, 10.0f, 3.1622776601683795f,
                           1.0f, 0.31622776601683794f, 0.1f, 0.031622776601683791f};

    half2v skck[4][8];
#pragma unroll
    for (int e = 0; e < 4; e++) {
#pragma unroll
        for (int k = 0; k < 8; k++) {
            float a = xa[e] * invt[k];
            skck[e][k] = __builtin_amdgcn_cvt_pkrtz(__sinf(a), __cosf(a));
        }
    }

    // t4 in [0, 810000); per-batch float4 count = NM/4 = 202500
    const unsigned int b  = (unsigned int)t4 / 202500u;
    const unsigned int r4 = (unsigned int)t4 - b * 202500u;
    float* op = out + (size_t)b * NH * NM + (size_t)r4 * 4;

#pragma unroll 1
    for (int pass = 0; pass < 4; pass++) {       // 2 heads per pass
        half2v w0[8], w1[8];
#pragma unroll
        for (int k = 0; k < 8; k++) {
            h2u u0; u0.u = __builtin_amdgcn_readfirstlane(wpk[pass * 16 + k]);
            h2u u1; u1.u = __builtin_amdgcn_readfirstlane(wpk[pass * 16 + 8 + k]);
            w0[k] = u0.h; w1[k] = u1.h;
        }
        h2u ub0; ub0.u = __builtin_amdgcn_readfirstlane(wpk[64 + 2 * pass]);
        h2u ub1; ub1.u = __builtin_amdgcn_readfirstlane(wpk[64 + 2 * pass + 1]);
        const float b0 = ub0.f, b1 = ub1.f;

        float o0[4], o1[4];
#pragma unroll
        for (int e = 0; e < 4; e++) {
            float a0 = b0, a1 = b1;
#pragma unroll
            for (int k = 0; k < 8; k++) {
                a0 = fdot2f(skck[e][k], w0[k], a0);
                a1 = fdot2f(skck[e][k], w1[k], a1);
            }
            o0[e] = fmaxf(a0, 0.f);
            o1[e] = fmaxf(a1, 0.f);
        }
        f4v s0 = {o0[0], o0[1], o0[2], o0[3]};
        f4v s1 = {o1[0], o1[1], o1[2], o1[3]};
        __builtin_nontemporal_store(s0, (f4v*)(op + (size_t)(2 * pass + 0) * NM));
        __builtin_nontemporal_store(s1, (f4v*)(op + (size_t)(2 * pass + 1) * NM));
    }
}

extern "C" void kernel_launch(void* const* d_in, const int* in_sizes, int n_in,
                              void* d_out, int out_size, void* d_ws, size_t ws_size,
                              hipStream_t stream) {
    const float* queries = (const float*)d_in[0];
    const float* cur_ref = (const float*)d_in[1];
    // d_in[2] = prev_ref_points: unused by the reference
    const float* vote_w  = (const float*)d_in[3];
    const float* vote_b  = (const float*)d_in[4];
    const float* proj_w  = (const float*)d_in[5];
    const float* proj_b  = (const float*)d_in[6];
    float* out  = (float*)d_out;
    float* xbuf = (float*)d_ws;                        // TOTAL floats = 12.96 MB
    unsigned int* wpk = (unsigned int*)(xbuf + TOTAL); // 72 dwords packed weights

    hough_pack<<<1, 128, 0, stream>>>(proj_w, proj_b, wpk);
    hough_imap<<<NB * NN, 256, 0, stream>>>(queries, cur_ref, vote_w, vote_b, xbuf);
    hough_epi<<<(TOTAL4 + 255) / 256, 256, 0, stream>>>(xbuf, wpk, out);
}

// Round 8
// 149.121 us; speedup vs baseline: 1.0553x; 1.0553x over previous
//
#include <hip/hip_runtime.h>

#define NPF 16
#define NH 8
#define NV 16
#define NN 900
#define ND 256
#define NB 4
#define NM (NN * NN)          // 810000

typedef __fp16 half2v __attribute__((ext_vector_type(2)));
union h2u { half2v h; unsigned int u; float f; };

#if __has_builtin(__builtin_amdgcn_fdot2)
__device__ __forceinline__ float fdot2f(half2v a, half2v b, float c) {
    return __builtin_amdgcn_fdot2(a, b, c, false);
}
#else
__device__ __forceinline__ float fdot2f(half2v a, half2v b, float c) {
    return fmaf((float)a.x, (float)b.x, fmaf((float)a.y, (float)b.y, c));
}
#endif

__device__ __forceinline__ float uloadf(const float* p) {
    return __int_as_float(__builtin_amdgcn_readfirstlane(__float_as_int(*p)));
}

__global__ __launch_bounds__(256)
__attribute__((amdgpu_waves_per_eu(4, 8)))
void hough_fused(
    const float* __restrict__ queries,
    const float* __restrict__ cur_ref,
    const float* __restrict__ vote_w,
    const float* __restrict__ vote_b,
    const float* __restrict__ proj_w,
    const float* __restrict__ proj_b,
    float* __restrict__ out)
{
    __shared__ __align__(16) float qs[ND];
    __shared__ float part[256];
    __shared__ float vp[NV * 2];
    __shared__ float s2i[NV];
    __shared__ __align__(16) float4 sCoef[NV];
    __shared__ float red[4];
    __shared__ float s_inv;

    const int tid = threadIdx.x;
    const int bn  = blockIdx.x;
    const int b   = bn / NN;
    const int n   = bn - b * NN;

    // ---- stage query row ----
    qs[tid] = queries[(size_t)bn * ND + tid];
    __syncthreads();

    // ---- votes: 32 outputs, 8 threads each over D=256 ----
    {
        const int o     = tid & 31;
        const int chunk = tid >> 5;
        const float4* wv = (const float4*)(vote_w + o * ND + chunk * 32);
        const float4* qv = (const float4*)(qs + chunk * 32);
        float p = 0.f;
#pragma unroll
        for (int j = 0; j < 8; j++) {
            float4 w4 = wv[j];
            float4 q4 = qv[j];
            p += w4.x * q4.x + w4.y * q4.y + w4.z * q4.z + w4.w * q4.w;
        }
        part[tid] = p;
    }
    __syncthreads();

    if (tid < 32) {
        float s = vote_b[tid];
#pragma unroll
        for (int c = 0; c < 8; c++) s += part[c * 32 + tid];
        vp[tid] = s + cur_ref[((size_t)b * NN + n) * 4 + (tid & 1)];
    } else if (tid >= 64 && tid < 64 + NV) {
        // sigma quirk: sigma_flat[b, i] = sigma[b, i % N], i = n*V + v
        int v = tid - 64;
        int j = (n * NV + v) % NN;
        float c2 = cur_ref[((size_t)b * NN + j) * 4 + 2];
        float c3 = cur_ref[((size_t)b * NN + j) * 4 + 3];
        float sg = (c2 + c3) * 0.25f;   // mean(c2,c3)/2
        s2i[v] = 0.5f / (sg * sg);
    }
    __syncthreads();

    // fold: exponent(m,v) = min(C0 + Ax*cx + Ay*cy + nS*cc, 0)
    if (tid < NV) {
        float x  = vp[2 * tid];
        float y  = vp[2 * tid + 1];
        float s2 = s2i[tid];
        sCoef[tid] = make_float4(2.f * s2 * x, 2.f * s2 * y,
                                 -s2 * (x * x + y * y), -s2);
    }
    __syncthreads();

    // ---- imap: per-thread m = tid + 256*i ----
    float acc[4] = {0.f, 0.f, 0.f, 0.f};
    const float4* cr4 = (const float4*)cur_ref + (size_t)b * NN;

#pragma unroll 1
    for (int c = 0; c < 2; c++) {       // two chunks of 8 votes, ~32 coeff regs
        float ax[8], ay[8], c0[8], ns[8];
#pragma unroll
        for (int v = 0; v < 8; v++) {
            float4 f = sCoef[c * 8 + v];   // LDS broadcast
            ax[v] = f.x; ay[v] = f.y; c0[v] = f.z; ns[v] = f.w;
        }
#pragma unroll
        for (int i = 0; i < 4; i++) {
            int m = tid + 256 * i;
            if (m < NN) {
                float4 cr = cr4[m];
                float cx = cr.x, cy = cr.y;
                float cc = cx * cx + cy * cy;
                float a = 0.f;
#pragma unroll
                for (int v = 0; v < 8; v++) {
                    float t = fmaf(ax[v], cx, c0[v]);
                    t = fmaf(ay[v], cy, t);
                    t = fmaf(ns[v], cc, t);
                    a += __expf(fminf(t, 0.f));
                }
                acc[i] += a;
            }
        }
    }

    // ---- block reduce (acc >= 0, |.| redundant) ----
    float lsum = acc[0] + acc[1] + acc[2] + acc[3];
#pragma unroll
    for (int off = 32; off > 0; off >>= 1) lsum += __shfl_down(lsum, off, 64);
    if ((tid & 63) == 0) red[tid >> 6] = lsum;
    __syncthreads();
    if (tid == 0)
        s_inv = 1.0f / fmaxf(red[0] + red[1] + red[2] + red[3], 1e-12f);
    __syncthreads();
    const float inv = s_inv;

    // ---- trig once per element, packed (sin,cos) half2: 32 VGPRs ----
    const float invt[8] = {100.0f, 31.622776601683793f, 10.0f, 3.1622776601683795f,
                           1.0f, 0.31622776601683794f, 0.1f, 0.031622776601683791f};
    half2v skck[4][8];
#pragma unroll
    for (int i = 0; i < 4; i++) {
        float x = 1.0f - acc[i] * inv;
#pragma unroll
        for (int k = 0; k < 8; k++) {
            float a = x * invt[k];
            skck[i][k] = __builtin_amdgcn_cvt_pkrtz(__sinf(a), __cosf(a));
        }
    }

    // ---- weights: SGPR-resident packed half2 (uniform loads, no LDS/VGPR cost) ----
    half2v W[64];
#pragma unroll
    for (int j = 0; j < 64; j++) {
        h2u u;
        u.h = __builtin_amdgcn_cvt_pkrtz(uloadf(proj_w + 2 * j),
                                         uloadf(proj_w + 2 * j + 1));
        u.u = __builtin_amdgcn_readfirstlane(u.u);
        W[j] = u.h;
    }
    float Pb[NH];
#pragma unroll
    for (int h = 0; h < NH; h++) Pb[h] = uloadf(proj_b + h);

    // ---- projection + relu + store: all 8 heads per element ----
    float* outrow = out + ((size_t)(b * NH) * NN + n) * NN;
#pragma unroll
    for (int i = 0; i < 4; i++) {
        int m = tid + 256 * i;
        if (m < NN) {
            float* op = outrow + m;
#pragma unroll
            for (int h = 0; h < NH; h++) {
                float o = Pb[h];
#pragma unroll
                for (int k = 0; k < 8; k++)
                    o = fdot2f(skck[i][k], W[h * 8 + k], o);
                op[(size_t)h * NM] = fmaxf(o, 0.f);
            }
        }
    }
}

extern "C" void kernel_launch(void* const* d_in, const int* in_sizes, int n_in,
                              void* d_out, int out_size, void* d_ws, size_t ws_size,
                              hipStream_t stream) {
    const float* queries = (const float*)d_in[0];
    const float* cur_ref = (const float*)d_in[1];
    // d_in[2] = prev_ref_points: unused by the reference
    const float* vote_w  = (const float*)d_in[3];
    const float* vote_b  = (const float*)d_in[4];
    const float* proj_w  = (const float*)d_in[5];
    const float* proj_b  = (const float*)d_in[6];
    float* out = (float*)d_out;

    hough_fused<<<NB * NN, 256, 0, stream>>>(queries, cur_ref, vote_w, vote_b,
                                             proj_w, proj_b, out);
}